// Round 10
// baseline (397.136 us; speedup 1.0000x reference)
//
#include <hip/hip_runtime.h>
#include <hip/hip_bf16.h>
#include <stdint.h>
#include <math.h>

// Problem constants
#define B_    2
#define T_    2048
#define C_    2048
#define H_    16
#define D_    128
#define NQKV  6144      // 3*C
#define BT_   4096      // B*T

typedef __attribute__((ext_vector_type(8)))  short short8;   // 8 bf16 (4 VGPR) MFMA A/B frag
typedef __attribute__((ext_vector_type(4)))  short short4_;  // 4 bf16 (8B)
typedef __attribute__((ext_vector_type(4)))  float float4_;  // 16x16 MFMA C/D frag
typedef __attribute__((ext_vector_type(16))) float f32x16;   // 32x32 MFMA C/D frag

__device__ __forceinline__ unsigned short f2bf(float f) {
  union { float f; unsigned int u; } v; v.f = f;
  unsigned int u = v.u;
  return (unsigned short)((u + 0x7FFFu + ((u >> 16) & 1u)) >> 16);  // RNE
}
__device__ __forceinline__ float bf2f(unsigned short u) {
  union { unsigned int i; float f; } v; v.i = ((unsigned int)u) << 16;
  return v.f;
}
// packed fp32x2 -> bf16x2
__device__ __forceinline__ void pk2(short4_& dst, int idx2, float a, float b) {
  union { __hip_bfloat162 h2; struct { short x, y; } s; } u;
  u.h2 = __float22bfloat162_rn(make_float2(a, b));
  dst[idx2 * 2]     = u.s.x;
  dst[idx2 * 2 + 1] = u.s.y;
}
// exchange an 8B value with lane^32
__device__ __forceinline__ short4_ shfl_xor32_s4(short4_ v) {
  union { short4_ s; int i[2]; } u; u.s = v;
  u.i[0] = __shfl_xor(u.i[0], 32);
  u.i[1] = __shfl_xor(u.i[1], 32);
  return u.s;
}

// async global->LDS, 16B per lane.  HW dest = wave-uniform base + lane*16,
// so LDS offsets must be contiguous in thread order (they are: base + tid*16).
__device__ __forceinline__ void async_cp16(const unsigned short* g, unsigned short* l) {
  __builtin_amdgcn_global_load_lds((__attribute__((address_space(1))) void*)g,
                                   (__attribute__((address_space(3))) void*)l,
                                   16, 0, 0);
}

// ----------------------------- fused fp32->bf16 (all 3 inputs) + trig tables
// Blocks 0..12287: bf16 conversion.  Blocks 12288..12799: RoPE trig tables
// ct/st[t*64+d] = cos/sin((sp+t) * 10000^(-d/64)).  Accurate sinf/cosf live
// HERE (tiny register footprint -> inlined; round-2 lesson: outlined trig
// inside the fat GEMM caused a scratch-write storm).
__global__ __launch_bounds__(256) void cvt_all(const float* __restrict__ x,
                                               const float* __restrict__ wqkv,
                                               const float* __restrict__ wproj,
                                               const int* __restrict__ sp_ptr,
                                               unsigned short* __restrict__ out,
                                               float* __restrict__ ct,
                                               float* __restrict__ st) {
  if (blockIdx.x >= 12288) {
    int j = (blockIdx.x - 12288) * 256 + threadIdx.x;   // 0..131071
    int d = j & 63;
    const float L2F = -0.20762050593046013f;  // -log2(10000)/64
    float fr = exp2f((float)d * L2F);
    float ang = (float)(sp_ptr[0] + (j >> 6)) * fr;
    ct[j] = cosf(ang);
    st[j] = sinf(ang);
    return;
  }
  int i = (blockIdx.x * 256 + threadIdx.x) * 8;   // 0 .. 25165824-8
  const float* src; int off;
  if (i < 8388608)       { src = x;     off = i; }
  else if (i < 20971520) { src = wqkv;  off = i - 8388608; }
  else                   { src = wproj; off = i - 20971520; }
  const float4_* p = (const float4_*)(src + off);
  float4_ a = p[0], b = p[1];
  short8 o;
  o[0] = (short)f2bf(a[0]); o[1] = (short)f2bf(a[1]);
  o[2] = (short)f2bf(a[2]); o[3] = (short)f2bf(a[3]);
  o[4] = (short)f2bf(b[0]); o[5] = (short)f2bf(b[1]);
  o[6] = (short)f2bf(b[2]); o[7] = (short)f2bf(b[3]);
  *(short8*)(out + i) = o;
}

// ------------------------------------------------------- GEMM  C = A * B^T
// (frozen m97-structure 128x128 kernel — used for the projection GEMM)
template <bool F32OUT>
__global__ __launch_bounds__(256) void gemm_bt(const unsigned short* __restrict__ A,
                                               const unsigned short* __restrict__ Bm,
                                               void* __restrict__ Cout,
                                               int M, int N, int K) {
  __shared__ __align__(16) unsigned short As[128 * 64];
  __shared__ __align__(16) unsigned short Bs[128 * 64];
  const int tid  = threadIdx.x;
  const int lane = tid & 63;
  const int col16 = lane & 15, quad = lane >> 4;
  const int wave = tid >> 6;
  const int wm = wave >> 1, wn = wave & 1;
  const int m0 = blockIdx.y * 128, n0 = blockIdx.x * 128;

  float4_ acc[4][4] = {};

  #pragma unroll 1
  for (int k0 = 0; k0 < K; k0 += 64) {
    __syncthreads();
    #pragma unroll
    for (int i = 0; i < 4; ++i) {
      int P   = i * 256 + tid;
      int row = P >> 3;                    // tile row 0..127
      int kc  = (P & 7) ^ (row & 7);       // logical chunk for this phys slot
      async_cp16(A  + (size_t)(m0 + row) * K + k0 + kc * 8, As + P * 8);
      async_cp16(Bm + (size_t)(n0 + row) * K + k0 + kc * 8, Bs + P * 8);
    }
    __syncthreads();
    #pragma unroll
    for (int ks = 0; ks < 2; ++ks) {
      short8 af[4], bf[4];
      #pragma unroll
      for (int i = 0; i < 4; ++i) {
        int ra = wm * 64 + i * 16 + col16;
        int ca = ((ks * 4 + quad) ^ (ra & 7)) * 8;
        af[i] = *(const short8*)(As + ra * 64 + ca);
        int rb = wn * 64 + i * 16 + col16;
        int cb = ((ks * 4 + quad) ^ (rb & 7)) * 8;
        bf[i] = *(const short8*)(Bs + rb * 64 + cb);
      }
      #pragma unroll
      for (int i = 0; i < 4; ++i)
        #pragma unroll
        for (int j = 0; j < 4; ++j)
          acc[i][j] = __builtin_amdgcn_mfma_f32_16x16x32_bf16(af[i], bf[j], acc[i][j], 0, 0, 0);
    }
  }

  // epilogue: C/D layout col=lane&15 (n), row=quad*4+reg (m)
  #pragma unroll
  for (int i = 0; i < 4; ++i) {
    int mg = m0 + wm * 64 + i * 16 + quad * 4;
    #pragma unroll
    for (int j = 0; j < 4; ++j) {
      int ng = n0 + wn * 64 + j * 16 + col16;
      #pragma unroll
      for (int r = 0; r < 4; ++r) {
        if constexpr (F32OUT)
          ((float*)Cout)[(size_t)(mg + r) * N + ng] = acc[i][j][r];
        else
          ((unsigned short*)Cout)[(size_t)(mg + r) * N + ng] = f2bf(acc[i][j][r]);
      }
    }
  }
}

// ---------------------------------------- GEMM1 + fused RoPE/split/V-transpose
// Round-3 configuration EXACTLY (best measured fused variant: 137-138 us,
// VGPR 112, 4 blk/CU).  Rounds 4-7: three VGPR-diet attempts all failed; the
// RoPE-pair epilogue's acc live-range sets a 112-VGPR floor.  Accepted.
// B-fragment row mapping per j: rb = wn*32+(j&1)*16+(j>>1)*64+c16, so
// acc[i][j]/acc[i][j+2] hold the RoPE pair (d, d+64) in the same lane.
// Each 128-wide n-tile is one head of Q, K or V (block-uniform epilogue mode).
__global__ __launch_bounds__(256) void gemm_qkv(const unsigned short* __restrict__ A,
                                                const unsigned short* __restrict__ Bm,
                                                const float* __restrict__ ct,
                                                const float* __restrict__ st,
                                                unsigned short* __restrict__ q_r,
                                                unsigned short* __restrict__ k_r,
                                                unsigned short* __restrict__ v_t) {
  __shared__ __align__(16) unsigned short S[16384];  // As = S[0:8192), Bs = S[8192:16384)
  unsigned short* As = S;
  unsigned short* Bs = S + 8192;
  const int tid  = threadIdx.x;
  const int lane = tid & 63;
  const int col16 = lane & 15, quad = lane >> 4;
  const int wave = tid >> 6;
  const int wm = wave >> 1, wn = wave & 1;
  const int m0 = blockIdx.y * 128, n0 = blockIdx.x * 128;

  float4_ acc[4][4] = {};

  #pragma unroll 1
  for (int k0 = 0; k0 < C_; k0 += 64) {
    __syncthreads();
    #pragma unroll
    for (int i = 0; i < 4; ++i) {
      int P   = i * 256 + tid;
      int row = P >> 3;
      int kc  = (P & 7) ^ (row & 7);
      async_cp16(A  + (size_t)(m0 + row) * C_ + k0 + kc * 8, As + P * 8);
      async_cp16(Bm + (size_t)(n0 + row) * C_ + k0 + kc * 8, Bs + P * 8);
    }
    __syncthreads();
    #pragma unroll
    for (int ks = 0; ks < 2; ++ks) {
      short8 af[4], bf[4];
      #pragma unroll
      for (int i = 0; i < 4; ++i) {
        int ra = wm * 64 + i * 16 + col16;
        int ca = ((ks * 4 + quad) ^ (ra & 7)) * 8;
        af[i] = *(const short8*)(As + ra * 64 + ca);
        // paired mapping: j={0,1} -> d in [wn*32, wn*32+32); j={2,3} -> +64
        int rb = wn * 32 + (i & 1) * 16 + (i >> 1) * 64 + col16;
        int cb = ((ks * 4 + quad) ^ (rb & 7)) * 8;
        bf[i] = *(const short8*)(Bs + rb * 64 + cb);
      }
      #pragma unroll
      for (int i = 0; i < 4; ++i)
        #pragma unroll
        for (int j = 0; j < 4; ++j)
          acc[i][j] = __builtin_amdgcn_mfma_f32_16x16x32_bf16(af[i], bf[j], acc[i][j], 0, 0, 0);
    }
  }

  // -------- fused epilogue --------
  const int region = n0 >> 11;           // 0=Q, 1=K, 2=V
  const int h   = (n0 & 2047) >> 7;      // head
  const int b   = m0 >> 11;              // batch (BM=128 never straddles b)
  const int t0l = m0 & 2047;             // token base within batch
  const int bh  = b * H_ + h;

  if (region < 2) {
    // ---- Q/K: register-local RoPE (pair (d, d+64) = acc[i][jl] / acc[i][jl+2])
    unsigned short* dst = region ? k_r : q_r;
    const float scl = region ? 1.0f : 0.1275174117f;  // Q: (1/sqrt(128))*log2(e)
    #pragma unroll
    for (int i = 0; i < 4; ++i) {
      int tl = t0l + wm * 64 + i * 16 + quad * 4;     // token (local to batch), +r below
      #pragma unroll
      for (int jl = 0; jl < 2; ++jl) {
        int d = wn * 32 + jl * 16 + col16;            // 0..63 (lo half)
        size_t ob = (size_t)(bh * T_ + tl) * D_ + d;
        int ti = tl * 64 + d;
        #pragma unroll
        for (int r = 0; r < 4; ++r) {
          float cs = ct[ti + r * 64], sn = st[ti + r * 64];
          float lo = acc[i][jl][r], hi = acc[i][jl + 2][r];
          dst[ob + (size_t)r * D_]      = f2bf((lo * cs - hi * sn) * scl);
          dst[ob + (size_t)r * D_ + 64] = f2bf((lo * sn + hi * cs) * scl);
        }
      }
    }
  } else {
    // ---- V: transpose via LDS (reuse S, 32 KB = exactly the 128x128 bf16 tile)
    __syncthreads();   // all waves done reading As/Bs from the main loop
    #pragma unroll
    for (int i = 0; i < 4; ++i) {
      int tlb = wm * 64 + i * 16 + quad * 4;          // local token 0..127
      #pragma unroll
      for (int j = 0; j < 4; ++j) {
        int d = wn * 32 + (j & 1) * 16 + (j >> 1) * 64 + col16;
        #pragma unroll
        for (int r = 0; r < 4; ++r) {
          int t = tlb + r;
          int ch = (t >> 3) ^ (d & 15);               // chunk swizzle (~2-way)
          S[d * 128 + ch * 8 + (t & 7)] = f2bf(acc[i][j][r]);
        }
      }
    }
    __syncthreads();
    // coalesced write: 2 threads per d-row, 128 B each
    int drow = tid >> 1, hf = tid & 1;
    size_t gb = (size_t)(bh * D_ + drow) * T_ + t0l + hf * 64;
    #pragma unroll
    for (int cc = 0; cc < 8; ++cc) {
      int ch = (hf * 8 + cc) ^ (drow & 15);
      *(short8*)(v_t + gb + cc * 8) = *(const short8*)(S + drow * 128 + ch * 8);
    }
  }
}

// ------------------------------------------------------- flash attention v6
// v5 (32x32 MFMA, verified layouts) + two m214-proven critical-path cuts:
// (a) In-register P (T12-equivalent): PV's B-operand is assembled from the
//     QK^T accumulator via cvt + shfl_xor(32) — the lane pair (l, l+32)
//     exchange their 4-run halves to form the k = 16*ks2+8*hi+e 8-runs.
//     Deletes the Ps LDS buffer (80 -> 64 KB), the 8 ds_writes + full
//     lgkmcnt(0) drain + 4 ds_reads per tile that sat mid-tile on the
//     serial critical path.
// (b) Defer-max (T13): skip the oacc rescale & max update when
//     __all(rm <= m_i + 11.5) (THR=8 in exp units -> 8*log2e in log2
//     domain).  Exact math on the skip branch (alpha=1); P bounded by
//     2^11.5, safe in bf16/f32.
// Grid 512 (16 qt x 32 bh), qt=(g<8?g:23-g) pairing, 256 thr, 2 blocks/CU.
__global__ __launch_bounds__(256) void attn_fwd(const unsigned short* __restrict__ q_r,
                                                const unsigned short* __restrict__ k_r,
                                                const unsigned short* __restrict__ v_t,
                                                unsigned short* __restrict__ Ob) {
  __shared__ __align__(16) unsigned short Ks[2][64 * 128];   // [s][d] swizzled, dbuf
  __shared__ __align__(16) unsigned short Vts[2][128 * 64];  // [d][s] swizzled, dbuf
  const int g     = blockIdx.x >> 5;   // 0..15
  const int bh    = blockIdx.x & 31;   // low bits -> XCD locality by head
  const int qt    = (g < 8) ? g : 23 - g;   // balanced co-residency pairing
  const int tid  = threadIdx.x;
  const int lane = tid & 63;
  const int l31  = lane & 31;
  const int hi   = lane >> 5;          // k-half selector
  const int w    = tid >> 6;           // wave 0..3
  const float NEG_INF = -__builtin_inff();
  const int b = bh >> 4, h = bh & 15;
  const int qlr = w * 32 + l31;        // this lane's q row within the 128-tile

  const int q0 = qt * 128;
  const int njt = 2 * qt + 2;          // 64-row kv tiles

  // Q frags (B-operand): B[k = ks*16 + hi*8 + e][n = qlr]  (pre-scaled)
  short8 qf[8];
  const unsigned short* qp = q_r + (size_t)(bh * T_ + q0 + qlr) * D_;
  #pragma unroll
  for (int ks = 0; ks < 8; ++ks) qf[ks] = *(const short8*)(qp + ks * 16 + hi * 8);

  f32x16 oacc[4] = {};
  float m_i = NEG_INF, l_i = 0.f;

  const unsigned short* kbase = k_r + (size_t)bh * T_ * D_;
  const unsigned short* vbase = v_t + (size_t)bh * D_ * T_;
  #define STAGE(JT, BUF)                                                        \
    {                                                                           \
      const unsigned short* kb = kbase + (size_t)(JT) * 64 * D_;                \
      const unsigned short* vb = vbase + (size_t)(JT) * 64;                     \
      unsigned short* kd = &Ks[(BUF)][0];                                       \
      unsigned short* vd = &Vts[(BUF)][0];                                      \
      _Pragma("unroll")                                                         \
      for (int i = 0; i < 4; ++i) {                                             \
        int P = i * 256 + tid;                                                  \
        int krow = P >> 4, kc = (P & 15) ^ (krow & 7);                          \
        async_cp16(kb + krow * D_ + kc * 8, kd + P * 8);                        \
        int vrow = P >> 3, vc = (P & 7) ^ (vrow & 7);                           \
        async_cp16(vb + (size_t)vrow * T_ + vc * 8, vd + P * 8);                \
      }                                                                         \
    }

  STAGE(0, 0);

  #pragma unroll 1
  for (int jt = 0; jt < njt; ++jt) {
    __syncthreads();                    // tile jt landed; prior reads done
    if (jt + 1 < njt) STAGE(jt + 1, (jt + 1) & 1);

    // wave-uniform skip: this wave's 32 q-rows all above (before) this kv tile
    if (jt * 64 > q0 + w * 32 + 31) continue;

    const unsigned short* KsB  = &Ks[jt & 1][0];
    const unsigned short* VtsB = &Vts[jt & 1][0];

    // S^T tiles: A = K rows (m=s), B = Q (n=qrow); log2-softmax domain
    f32x16 s32[2];
    #pragma unroll
    for (int jn = 0; jn < 2; ++jn) {
      f32x16 a = {};
      #pragma unroll
      for (int ks = 0; ks < 8; ++ks) {
        int kr = jn * 32 + l31;
        int ch = ((ks * 2 + hi) ^ (kr & 7)) * 8;
        short8 kfr = *(const short8*)(KsB + kr * 128 + ch);
        a = __builtin_amdgcn_mfma_f32_32x32x16_bf16(kfr, qf[ks], a, 0, 0, 0);
      }
      s32[jn] = a;
    }
    if (jt * 64 + 63 > q0 + w * 32) {  // wave-uniform partial-mask branch
      #pragma unroll
      for (int jn = 0; jn < 2; ++jn)
        #pragma unroll
        for (int reg = 0; reg < 16; ++reg) {
          int mrow = (reg & 3) + 8 * (reg >> 2) + 4 * hi;
          if (jt * 64 + jn * 32 + mrow > q0 + qlr) s32[jn][reg] = NEG_INF;
        }
    }
    // online softmax (log2 domain); lane pair (l, l+32) share qrow
    float rm = NEG_INF;
    #pragma unroll
    for (int jn = 0; jn < 2; ++jn)
      #pragma unroll
      for (int reg = 0; reg < 16; ++reg) rm = fmaxf(rm, s32[jn][reg]);
    rm = fmaxf(rm, __shfl_xor(rm, 32));
    // defer-max: rescale only when the tile max exceeds m_i by > 11.5
    // (= e^8 bound on P).  First tile: m_i = -inf -> condition false ->
    // rescale path runs (alpha = 0, oacc already 0).
    if (!__all(rm <= m_i + 11.5f)) {
      float m_new = fmaxf(m_i, rm);
      float alpha = exp2f(m_i - m_new);
      l_i *= alpha;
      #pragma unroll
      for (int dt = 0; dt < 4; ++dt) oacc[dt] *= alpha;
      m_i = m_new;
    }
    float rs = 0.f;
    #pragma unroll
    for (int jn = 0; jn < 2; ++jn)
      #pragma unroll
      for (int reg = 0; reg < 16; ++reg) {
        float pv = exp2f(s32[jn][reg] - m_i);
        s32[jn][reg] = pv;
        rs += pv;
      }
    rs += __shfl_xor(rs, 32);
    l_i += rs;

    // ---- P assembly fully in-register (no LDS round-trip) ----
    // Lane (l31,hi) owns s_local = 8g + 4hi + {0..3} per jn.  Pack each
    // 4-run to bf16 (2 u32) and exchange with lane^32; frag ks2 = 2jn+q
    // needs s = 16ks2 + 8hi + e:  lo4(e=0..3) from the hi=0 lane's group
    // g1=2q+hi... assembled via compile-time-indexed cndmask selects.
    short8 pfv[4];
    #pragma unroll
    for (int jn = 0; jn < 2; ++jn) {
      short4_ pk[4], ot[4];
      #pragma unroll
      for (int gg = 0; gg < 4; ++gg) {
        pk2(pk[gg], 0, s32[jn][gg * 4 + 0], s32[jn][gg * 4 + 1]);
        pk2(pk[gg], 1, s32[jn][gg * 4 + 2], s32[jn][gg * 4 + 3]);
        ot[gg] = shfl_xor32_s4(pk[gg]);
      }
      #pragma unroll
      for (int q = 0; q < 2; ++q) {
        short4_ lo4 = hi ? ot[2 * q + 1] : pk[2 * q];
        short4_ hi4 = hi ? pk[2 * q + 1] : ot[2 * q];
        short8 bf_;
        bf_[0] = lo4[0]; bf_[1] = lo4[1]; bf_[2] = lo4[2]; bf_[3] = lo4[3];
        bf_[4] = hi4[0]; bf_[5] = hi4[1]; bf_[6] = hi4[2]; bf_[7] = hi4[3];
        pfv[jn * 2 + q] = bf_;
      }
    }

    // O^T += V^T · P^T : A = Vts (m=d), B = P frags (n=qrow), in-register
    #pragma unroll
    for (int dt = 0; dt < 4; ++dt)
      #pragma unroll
      for (int ks2 = 0; ks2 < 4; ++ks2) {
        int vr = dt * 32 + l31;
        int ch = ((ks2 * 2 + hi) ^ (vr & 7)) * 8;
        short8 vf = *(const short8*)(VtsB + vr * 64 + ch);
        oacc[dt] = __builtin_amdgcn_mfma_f32_32x32x16_bf16(vf, pfv[ks2], oacc[dt], 0, 0, 0);
      }
  }

  // epilogue: O^T layout col=lane&31=qrow, row d = dt*32 + (reg&3)+8(reg>>2)+4hi
  float inv_l = 1.0f / l_i;
  size_t ob = (size_t)(b * T_ + q0 + qlr) * C_ + h * D_;
  #pragma unroll
  for (int dt = 0; dt < 4; ++dt)
    #pragma unroll
    for (int gg = 0; gg < 4; ++gg) {
      int d = dt * 32 + 8 * gg + 4 * hi;
      short4_ o4;
      pk2(o4, 0, oacc[dt][gg * 4 + 0] * inv_l, oacc[dt][gg * 4 + 1] * inv_l);
      pk2(o4, 1, oacc[dt][gg * 4 + 2] * inv_l, oacc[dt][gg * 4 + 3] * inv_l);
      *(short4_*)(Ob + ob + d) = o4;
    }
  #undef STAGE
}

// ---------------------------------------------------------------- launcher
extern "C" void kernel_launch(void* const* d_in, const int* in_sizes, int n_in,
                              void* d_out, int out_size, void* d_ws, size_t ws_size,
                              hipStream_t stream) {
  const float* x     = (const float*)d_in[0];
  const float* Wqkv  = (const float*)d_in[1];
  const float* Wproj = (const float*)d_in[2];
  const int*   sp    = (const int*)d_in[3];
  float* out = (float*)d_out;

  unsigned short* ws     = (unsigned short*)d_ws;
  unsigned short* xb     = ws;                    //  8,388,608
  unsigned short* wqkvb  = xb + 8388608;          // 12,582,912
  unsigned short* wprojb = wqkvb + 12582912;      //  4,194,304
  unsigned short* q_r    = wprojb + 4194304;      //  8,388,608
  unsigned short* k_r    = q_r + 8388608;         //  8,388,608
  unsigned short* v_t    = k_r + 8388608;         //  8,388,608
  float*          ctab   = (float*)(v_t + 8388608);  // 131,072 f32
  float*          stab   = ctab + 131072;            // 131,072 f32
  unsigned short* Obuf   = xb;                    // alias: xb dead after GEMM1

  // bf16 conversion + trig tables in one launch (trig blocks at the tail)
  cvt_all<<<12800, 256, 0, stream>>>(x, Wqkv, Wproj, sp, ws, ctab, stab);

  // QKV projection with fused RoPE/split/V-transpose (round-3 config)
  gemm_qkv<<<dim3(48, 32), 256, 0, stream>>>(xb, wqkvb, ctab, stab, q_r, k_r, v_t);

  // attention: 512 blocks x 256 threads, in-register P, defer-max
  attn_fwd<<<dim3(512), 256, 0, stream>>>(q_r, k_r, v_t, Obuf);

  gemm_bt<true><<<dim3(16, 32), 256, 0, stream>>>(Obuf, wprojb, (void*)out, BT_, C_, C_);
}

// Round 11
// 367.453 us; speedup vs baseline: 1.0808x; 1.0808x over previous
//
#include <hip/hip_runtime.h>
#include <hip/hip_bf16.h>
#include <stdint.h>
#include <math.h>

// Problem constants
#define B_    2
#define T_    2048
#define C_    2048
#define H_    16
#define D_    128
#define NQKV  6144      // 3*C
#define BT_   4096      // B*T

typedef __attribute__((ext_vector_type(8))) short  short8;   // 8 bf16 (4 VGPR) MFMA A/B frag
typedef __attribute__((ext_vector_type(4))) short  short4_;  // 4 bf16 (8B)
typedef __attribute__((ext_vector_type(4))) float  float4_;  // MFMA C/D frag

__device__ __forceinline__ unsigned short f2bf(float f) {
  union { float f; unsigned int u; } v; v.f = f;
  unsigned int u = v.u;
  return (unsigned short)((u + 0x7FFFu + ((u >> 16) & 1u)) >> 16);  // RNE
}
__device__ __forceinline__ float bf2f(unsigned short u) {
  union { unsigned int i; float f; } v; v.i = ((unsigned int)u) << 16;
  return v.f;
}
// packed fp32x2 -> bf16x2
__device__ __forceinline__ void pk2(short4_& dst, int idx2, float a, float b) {
  union { __hip_bfloat162 h2; struct { short x, y; } s; } u;
  u.h2 = __float22bfloat162_rn(make_float2(a, b));
  dst[idx2 * 2]     = u.s.x;
  dst[idx2 * 2 + 1] = u.s.y;
}

// async global->LDS, 16B per lane.  HW dest = wave-uniform base + lane*16,
// so LDS offsets must be contiguous in thread order (they are: base + tid*16).
__device__ __forceinline__ void async_cp16(const unsigned short* g, unsigned short* l) {
  __builtin_amdgcn_global_load_lds((__attribute__((address_space(1))) void*)g,
                                   (__attribute__((address_space(3))) void*)l,
                                   16, 0, 0);
}

// ----------------------------- fused fp32->bf16 (all 3 inputs) + trig tables
// Blocks 0..12287: bf16 conversion.  Blocks 12288..12799: RoPE trig tables
// ct/st[t*64+d] = cos/sin((sp+t) * 10000^(-d/64)).  Accurate sinf/cosf live
// HERE (tiny register footprint -> inlined; round-2 lesson: outlined trig
// inside the fat GEMM caused a scratch-write storm).
__global__ __launch_bounds__(256) void cvt_all(const float* __restrict__ x,
                                               const float* __restrict__ wqkv,
                                               const float* __restrict__ wproj,
                                               const int* __restrict__ sp_ptr,
                                               unsigned short* __restrict__ out,
                                               float* __restrict__ ct,
                                               float* __restrict__ st) {
  if (blockIdx.x >= 12288) {
    int j = (blockIdx.x - 12288) * 256 + threadIdx.x;   // 0..131071
    int d = j & 63;
    const float L2F = -0.20762050593046013f;  // -log2(10000)/64
    float fr = exp2f((float)d * L2F);
    float ang = (float)(sp_ptr[0] + (j >> 6)) * fr;
    ct[j] = cosf(ang);
    st[j] = sinf(ang);
    return;
  }
  int i = (blockIdx.x * 256 + threadIdx.x) * 8;   // 0 .. 25165824-8
  const float* src; int off;
  if (i < 8388608)       { src = x;     off = i; }
  else if (i < 20971520) { src = wqkv;  off = i - 8388608; }
  else                   { src = wproj; off = i - 20971520; }
  const float4_* p = (const float4_*)(src + off);
  float4_ a = p[0], b = p[1];
  short8 o;
  o[0] = (short)f2bf(a[0]); o[1] = (short)f2bf(a[1]);
  o[2] = (short)f2bf(a[2]); o[3] = (short)f2bf(a[3]);
  o[4] = (short)f2bf(b[0]); o[5] = (short)f2bf(b[1]);
  o[6] = (short)f2bf(b[2]); o[7] = (short)f2bf(b[3]);
  *(short8*)(out + i) = o;
}

// ------------------------------------------------------- GEMM  C = A * B^T
// (frozen m97-structure 128x128 kernel — used for the projection GEMM)
template <bool F32OUT>
__global__ __launch_bounds__(256) void gemm_bt(const unsigned short* __restrict__ A,
                                               const unsigned short* __restrict__ Bm,
                                               void* __restrict__ Cout,
                                               int M, int N, int K) {
  __shared__ __align__(16) unsigned short As[128 * 64];
  __shared__ __align__(16) unsigned short Bs[128 * 64];
  const int tid  = threadIdx.x;
  const int lane = tid & 63;
  const int col16 = lane & 15, quad = lane >> 4;
  const int wave = tid >> 6;
  const int wm = wave >> 1, wn = wave & 1;
  const int m0 = blockIdx.y * 128, n0 = blockIdx.x * 128;

  float4_ acc[4][4] = {};

  #pragma unroll 1
  for (int k0 = 0; k0 < K; k0 += 64) {
    __syncthreads();
    #pragma unroll
    for (int i = 0; i < 4; ++i) {
      int P   = i * 256 + tid;
      int row = P >> 3;                    // tile row 0..127
      int kc  = (P & 7) ^ (row & 7);       // logical chunk for this phys slot
      async_cp16(A  + (size_t)(m0 + row) * K + k0 + kc * 8, As + P * 8);
      async_cp16(Bm + (size_t)(n0 + row) * K + k0 + kc * 8, Bs + P * 8);
    }
    __syncthreads();
    #pragma unroll
    for (int ks = 0; ks < 2; ++ks) {
      short8 af[4], bf[4];
      #pragma unroll
      for (int i = 0; i < 4; ++i) {
        int ra = wm * 64 + i * 16 + col16;
        int ca = ((ks * 4 + quad) ^ (ra & 7)) * 8;
        af[i] = *(const short8*)(As + ra * 64 + ca);
        int rb = wn * 64 + i * 16 + col16;
        int cb = ((ks * 4 + quad) ^ (rb & 7)) * 8;
        bf[i] = *(const short8*)(Bs + rb * 64 + cb);
      }
      #pragma unroll
      for (int i = 0; i < 4; ++i)
        #pragma unroll
        for (int j = 0; j < 4; ++j)
          acc[i][j] = __builtin_amdgcn_mfma_f32_16x16x32_bf16(af[i], bf[j], acc[i][j], 0, 0, 0);
    }
  }

  // epilogue: C/D layout col=lane&15 (n), row=quad*4+reg (m)
  #pragma unroll
  for (int i = 0; i < 4; ++i) {
    int mg = m0 + wm * 64 + i * 16 + quad * 4;
    #pragma unroll
    for (int j = 0; j < 4; ++j) {
      int ng = n0 + wn * 64 + j * 16 + col16;
      #pragma unroll
      for (int r = 0; r < 4; ++r) {
        if constexpr (F32OUT)
          ((float*)Cout)[(size_t)(mg + r) * N + ng] = acc[i][j][r];
        else
          ((unsigned short*)Cout)[(size_t)(mg + r) * N + ng] = f2bf(acc[i][j][r]);
      }
    }
  }
}

// ---------------------------------------- GEMM1 + fused RoPE/split/V-transpose
// Main loop = round-3 config (identical to gemm_bt except the paired B-row
// mapping: rb = wn*32+(j&1)*16+(j>>1)*64+c16, so acc[i][j]/acc[i][j+2] hold
// the RoPE pair (d, d+64) in the same lane).  Each 128-wide n-tile is one
// head of Q, K or V (block-uniform epilogue mode).
//
// Round-11 epilogue restructure (the VGPR-112 fix, attempt #4 — different
// mechanism this time): rounds 4-7 kept the 64-VGPR f32 acc live through the
// whole trig+store sequence (dataflow-required — fences couldn't help).  Now:
//   phase A: pack acc -> 32 VGPRs of bf16 pairs (v_cvt_pk); acc DIES here.
//   sched_barrier(0): no ct/st loads may hoist above, no packs may sink below.
//   phase B: unpack bf16 -> f32, RoPE with table values, store.
// Nothing f32-wide crosses the phase boundary; peak live set should return
// to the main loop's ~88 -> 5 blocks/CU.  Numerics: RoPE on bf16-rounded
// GEMM output = exactly the round-0 rope_split path (passed, same absmax).
__global__ __launch_bounds__(256) void gemm_qkv(const unsigned short* __restrict__ A,
                                                const unsigned short* __restrict__ Bm,
                                                const float* __restrict__ ct,
                                                const float* __restrict__ st,
                                                unsigned short* __restrict__ q_r,
                                                unsigned short* __restrict__ k_r,
                                                unsigned short* __restrict__ v_t) {
  __shared__ __align__(16) unsigned short S[16384];  // As = S[0:8192), Bs = S[8192:16384)
  unsigned short* As = S;
  unsigned short* Bs = S + 8192;
  const int tid  = threadIdx.x;
  const int lane = tid & 63;
  const int col16 = lane & 15, quad = lane >> 4;
  const int wave = tid >> 6;
  const int wm = wave >> 1, wn = wave & 1;
  const int m0 = blockIdx.y * 128, n0 = blockIdx.x * 128;

  float4_ acc[4][4] = {};

  #pragma unroll 1
  for (int k0 = 0; k0 < C_; k0 += 64) {
    __syncthreads();
    #pragma unroll
    for (int i = 0; i < 4; ++i) {
      int P   = i * 256 + tid;
      int row = P >> 3;
      int kc  = (P & 7) ^ (row & 7);
      async_cp16(A  + (size_t)(m0 + row) * C_ + k0 + kc * 8, As + P * 8);
      async_cp16(Bm + (size_t)(n0 + row) * C_ + k0 + kc * 8, Bs + P * 8);
    }
    __syncthreads();
    #pragma unroll
    for (int ks = 0; ks < 2; ++ks) {
      short8 af[4], bf[4];
      #pragma unroll
      for (int i = 0; i < 4; ++i) {
        int ra = wm * 64 + i * 16 + col16;
        int ca = ((ks * 4 + quad) ^ (ra & 7)) * 8;
        af[i] = *(const short8*)(As + ra * 64 + ca);
        // paired mapping: j={0,1} -> d in [wn*32, wn*32+32); j={2,3} -> +64
        int rb = wn * 32 + (i & 1) * 16 + (i >> 1) * 64 + col16;
        int cb = ((ks * 4 + quad) ^ (rb & 7)) * 8;
        bf[i] = *(const short8*)(Bs + rb * 64 + cb);
      }
      #pragma unroll
      for (int i = 0; i < 4; ++i)
        #pragma unroll
        for (int j = 0; j < 4; ++j)
          acc[i][j] = __builtin_amdgcn_mfma_f32_16x16x32_bf16(af[i], bf[j], acc[i][j], 0, 0, 0);
    }
  }

  // -------- fused epilogue --------
  const int region = n0 >> 11;           // 0=Q, 1=K, 2=V
  const int h   = (n0 & 2047) >> 7;      // head
  const int b   = m0 >> 11;              // batch (BM=128 never straddles b)
  const int t0l = m0 & 2047;             // token base within batch
  const int bh  = b * H_ + h;

  if (region < 2) {
    // ---- phase A: pack acc pairs to bf16 (32 VGPRs); acc dies here.
    // pq[i][jl][0] = bf16(acc[i][jl][0..3])  (lo half values)
    // pq[i][jl][1] = bf16(acc[i][jl+2][0..3]) (hi half values)
    short4_ pq[4][2][2];
    #pragma unroll
    for (int i = 0; i < 4; ++i)
      #pragma unroll
      for (int jl = 0; jl < 2; ++jl) {
        pk2(pq[i][jl][0], 0, acc[i][jl][0],     acc[i][jl][1]);
        pk2(pq[i][jl][0], 1, acc[i][jl][2],     acc[i][jl][3]);
        pk2(pq[i][jl][1], 0, acc[i][jl + 2][0], acc[i][jl + 2][1]);
        pk2(pq[i][jl][1], 1, acc[i][jl + 2][2], acc[i][jl + 2][3]);
      }
    __builtin_amdgcn_sched_barrier(0);   // phase boundary: acc must be dead

    // ---- phase B: RoPE from packed values + trig tables, store bf16.
    unsigned short* dst = region ? k_r : q_r;
    const float scl = region ? 1.0f : 0.1275174117f;  // Q: (1/sqrt(128))*log2(e)
    #pragma unroll
    for (int i = 0; i < 4; ++i) {
      int tl = t0l + wm * 64 + i * 16 + quad * 4;     // token (local to batch), +r below
      #pragma unroll
      for (int jl = 0; jl < 2; ++jl) {
        int d = wn * 32 + jl * 16 + col16;            // 0..63 (lo half)
        size_t ob = (size_t)(bh * T_ + tl) * D_ + d;
        int ti = tl * 64 + d;
        #pragma unroll
        for (int r = 0; r < 4; ++r) {
          float cs = ct[ti + r * 64], sn = st[ti + r * 64];
          float lo = bf2f((unsigned short)pq[i][jl][0][r]);
          float hi = bf2f((unsigned short)pq[i][jl][1][r]);
          dst[ob + (size_t)r * D_]      = f2bf((lo * cs - hi * sn) * scl);
          dst[ob + (size_t)r * D_ + 64] = f2bf((lo * sn + hi * cs) * scl);
        }
      }
    }
  } else {
    // ---- V: transpose via LDS (reuse S, 32 KB = exactly the 128x128 bf16 tile)
    __syncthreads();   // all waves done reading As/Bs from the main loop
    #pragma unroll
    for (int i = 0; i < 4; ++i) {
      int tlb = wm * 64 + i * 16 + quad * 4;          // local token 0..127
      #pragma unroll
      for (int j = 0; j < 4; ++j) {
        int d = wn * 32 + (j & 1) * 16 + (j >> 1) * 64 + col16;
        #pragma unroll
        for (int r = 0; r < 4; ++r) {
          int t = tlb + r;
          int ch = (t >> 3) ^ (d & 15);               // chunk swizzle (~2-way)
          S[d * 128 + ch * 8 + (t & 7)] = f2bf(acc[i][j][r]);
        }
      }
    }
    __syncthreads();
    // coalesced write: 2 threads per d-row, 128 B each
    int drow = tid >> 1, hf = tid & 1;
    size_t gb = (size_t)(bh * D_ + drow) * T_ + t0l + hf * 64;
    #pragma unroll
    for (int cc = 0; cc < 8; ++cc) {
      int ch = (hf * 8 + cc) ^ (drow & 15);
      *(short8*)(v_t + gb + cc * 8) = *(const short8*)(S + drow * 128 + ch * 8);
    }
  }
}

// ------------------------------------------------------- flash attention v4
// (round-8 kernel EXACTLY — best measured total, 366.1 us.  Rounds 9/10
// falsified: 32x32 MFMA neutral, in-register-P + defer-max regressed.)
// 1 q-tile per block (grid 512 = 16 qt x 32 bh); LDS 80 KB x 2 = 160 KB/CU
// and __launch_bounds__(512,4) -> two co-resident blocks per CU.
// qt = (g<8 ? g : 23-g): co-resident blocks' qt sum to 15 -> uniform work.
__global__ __launch_bounds__(512, 4) void attn_fwd(const unsigned short* __restrict__ q_r,
                                                   const unsigned short* __restrict__ k_r,
                                                   const unsigned short* __restrict__ v_t,
                                                   unsigned short* __restrict__ Ob) {
  __shared__ __align__(16) unsigned short Ks[2][64 * 128];   // [s][d] swizzled, dbuf
  __shared__ __align__(16) unsigned short Vts[2][128 * 64];  // [d][s] swizzled, dbuf
  __shared__ __align__(16) unsigned short Ps[128 * 64];      // [qrow][s] swizzled
  const int g     = blockIdx.x >> 5;   // 0..15
  const int bh    = blockIdx.x & 31;   // low bits -> XCD locality by head
  const int qt    = (g < 8) ? g : 23 - g;   // balanced co-residency pairing
  const int tid  = threadIdx.x;
  const int lane = tid & 63;
  const int col16 = lane & 15, quad = lane >> 4;
  const int wave = tid >> 6;           // 0..7
  const float NEG_INF = -__builtin_inff();
  const int b = bh >> 4, h = bh & 15;
  const int qlr = wave * 16 + col16;   // this lane's q row within the 128-tile

  const int q0 = qt * 128;
  const int njt = 2 * qt + 2;                   // 64-row kv tiles

  // Q frags (B-operand): B[k=d][n=qrow], 8 contiguous d per lane (pre-scaled)
  short8 qf[4];
  const unsigned short* qp = q_r + (size_t)(bh * T_ + q0 + qlr) * D_;
  #pragma unroll
  for (int ks = 0; ks < 4; ++ks) qf[ks] = *(const short8*)(qp + ks * 32 + quad * 8);

  float4_ oacc[8] = {};
  float m_i = NEG_INF, l_i = 0.f;

  const unsigned short* kbase = k_r + (size_t)bh * T_ * D_;
  const unsigned short* vbase = v_t + (size_t)bh * D_ * T_;
  #define STAGE(JT, BUF)                                                        \
    {                                                                           \
      const unsigned short* kb = kbase + (size_t)(JT) * 64 * D_;                \
      const unsigned short* vb = vbase + (size_t)(JT) * 64;                     \
      unsigned short* kd = &Ks[(BUF)][0];                                       \
      unsigned short* vd = &Vts[(BUF)][0];                                      \
      _Pragma("unroll")                                                         \
      for (int i = 0; i < 2; ++i) {                                             \
        int P = i * 512 + tid;                                                  \
        int krow = P >> 4, kc = (P & 15) ^ (krow & 7);                          \
        async_cp16(kb + krow * D_ + kc * 8, kd + P * 8);                        \
        int vrow = P >> 3, vc = (P & 7) ^ (vrow & 7);                           \
        async_cp16(vb + (size_t)vrow * T_ + vc * 8, vd + P * 8);                \
      }                                                                         \
    }

  STAGE(0, 0);

  #pragma unroll 1
  for (int jt = 0; jt < njt; ++jt) {
    __syncthreads();                    // tile jt landed; prior reads done
    if (jt + 1 < njt) STAGE(jt + 1, (jt + 1) & 1);

    // wave-uniform skip: this wave's 16 q-rows all above (before) this kv tile
    if (jt * 64 > q0 + wave * 16 + 15) continue;

    const unsigned short* KsB  = &Ks[jt & 1][0];
    const unsigned short* VtsB = &Vts[jt & 1][0];

    // S^T tiles: A = K rows, B = Q  (values already in log2-softmax domain)
    float4_ s[4];
    #pragma unroll
    for (int jn = 0; jn < 4; ++jn) {
      float4_ a = {};
      #pragma unroll
      for (int ks = 0; ks < 4; ++ks) {
        int kr = jn * 16 + col16;
        int ch = ((ks * 4 + quad) ^ (kr & 7)) * 8;
        short8 kfr = *(const short8*)(KsB + kr * 128 + ch);
        a = __builtin_amdgcn_mfma_f32_16x16x32_bf16(kfr, qf[ks], a, 0, 0, 0);
      }
      s[jn] = a;
    }
    if (jt * 64 + 63 > q0 + wave * 16) {  // wave-uniform partial-mask branch
      #pragma unroll
      for (int jn = 0; jn < 4; ++jn)
        #pragma unroll
        for (int r = 0; r < 4; ++r)
          if (jt * 64 + jn * 16 + quad * 4 + r > q0 + qlr) s[jn][r] = NEG_INF;
    }
    // online softmax (log2 domain); stats per q row = per lane
    float rm = NEG_INF;
    #pragma unroll
    for (int jn = 0; jn < 4; ++jn)
      #pragma unroll
      for (int r = 0; r < 4; ++r) rm = fmaxf(rm, s[jn][r]);
    rm = fmaxf(rm, __shfl_xor(rm, 16));
    rm = fmaxf(rm, __shfl_xor(rm, 32));
    float m_new = fmaxf(m_i, rm);
    float alpha = exp2f(m_i - m_new);
    float rs = 0.f;
    #pragma unroll
    for (int jn = 0; jn < 4; ++jn)
      #pragma unroll
      for (int r = 0; r < 4; ++r) {
        float pv = exp2f(s[jn][r] - m_new);
        s[jn][r] = pv;
        rs += pv;
      }
    rs += __shfl_xor(rs, 16);
    rs += __shfl_xor(rs, 32);
    l_i = l_i * alpha + rs;
    m_i = m_new;
    #pragma unroll
    for (int dt = 0; dt < 8; ++dt) oacc[dt] *= alpha;

    // P -> LDS (wave-private rows), packed bf16
    #pragma unroll
    for (int jn = 0; jn < 4; ++jn) {
      short4_ pkv;
      pk2(pkv, 0, s[jn][0], s[jn][1]);
      pk2(pkv, 1, s[jn][2], s[jn][3]);
      int c0 = jn * 16 + quad * 4;
      int ch = (c0 >> 3) ^ (qlr & 7);
      *(short4_*)(Ps + qlr * 64 + ch * 8 + (c0 & 7)) = pkv;
    }
    __builtin_amdgcn_s_waitcnt(0xC07F);  // lgkmcnt(0): own P writes -> own reads

    // O^T += V^T · P^T : A = Vts (m=d), B = Ps rows (n=qrow)
    short8 pf[2];
    #pragma unroll
    for (int ks2 = 0; ks2 < 2; ++ks2) {
      int ch = ((ks2 * 4 + quad) ^ (qlr & 7)) * 8;
      pf[ks2] = *(const short8*)(Ps + qlr * 64 + ch);
    }
    #pragma unroll
    for (int dt = 0; dt < 8; ++dt)
      #pragma unroll
      for (int ks2 = 0; ks2 < 2; ++ks2) {
        int vr = dt * 16 + col16;
        int ch = ((ks2 * 4 + quad) ^ (vr & 7)) * 8;
        short8 vf = *(const short8*)(VtsB + vr * 64 + ch);
        oacc[dt] = __builtin_amdgcn_mfma_f32_16x16x32_bf16(vf, pf[ks2], oacc[dt], 0, 0, 0);
      }
  }

  // epilogue: O^T C-layout col=lane&15=qrow, row=quad*4+r=d
  float inv_l = 1.0f / l_i;
  size_t ob = (size_t)(b * T_ + q0 + qlr) * C_ + h * D_;
  #pragma unroll
  for (int dt = 0; dt < 8; ++dt) {
    short4_ o4;
    pk2(o4, 0, oacc[dt][0] * inv_l, oacc[dt][1] * inv_l);
    pk2(o4, 1, oacc[dt][2] * inv_l, oacc[dt][3] * inv_l);
    *(short4_*)(Ob + ob + dt * 16 + quad * 4) = o4;
  }
  #undef STAGE
}

// ---------------------------------------------------------------- launcher
extern "C" void kernel_launch(void* const* d_in, const int* in_sizes, int n_in,
                              void* d_out, int out_size, void* d_ws, size_t ws_size,
                              hipStream_t stream) {
  const float* x     = (const float*)d_in[0];
  const float* Wqkv  = (const float*)d_in[1];
  const float* Wproj = (const float*)d_in[2];
  const int*   sp    = (const int*)d_in[3];
  float* out = (float*)d_out;

  unsigned short* ws     = (unsigned short*)d_ws;
  unsigned short* xb     = ws;                    //  8,388,608
  unsigned short* wqkvb  = xb + 8388608;          // 12,582,912
  unsigned short* wprojb = wqkvb + 12582912;      //  4,194,304
  unsigned short* q_r    = wprojb + 4194304;      //  8,388,608
  unsigned short* k_r    = q_r + 8388608;         //  8,388,608
  unsigned short* v_t    = k_r + 8388608;         //  8,388,608
  float*          ctab   = (float*)(v_t + 8388608);  // 131,072 f32
  float*          stab   = ctab + 131072;            // 131,072 f32
  unsigned short* Obuf   = xb;                    // alias: xb dead after GEMM1

  // bf16 conversion + trig tables in one launch (trig blocks at the tail)
  cvt_all<<<12800, 256, 0, stream>>>(x, Wqkv, Wproj, sp, ws, ctab, stab);

  // QKV projection with fused RoPE/split/V-transpose (early-pack epilogue)
  gemm_qkv<<<dim3(48, 32), 256, 0, stream>>>(xb, wqkvb, ctab, stab, q_r, k_r, v_t);

  // attention: round-8 v4 (512 blocks x 512 threads, 2 blocks/CU)
  attn_fwd<<<dim3(512), 512, 0, stream>>>(q_r, k_r, v_t, Obuf);

  gemm_bt<true><<<dim3(16, 32), 256, 0, stream>>>(Obuf, wprojb, (void*)out, BT_, C_, C_);
}

// Round 12
// 363.125 us; speedup vs baseline: 1.0937x; 1.0119x over previous
//
#include <hip/hip_runtime.h>
#include <hip/hip_bf16.h>
#include <stdint.h>
#include <math.h>

// Problem constants
#define B_    2
#define T_    2048
#define C_    2048
#define H_    16
#define D_    128
#define NQKV  6144      // 3*C
#define BT_   4096      // B*T

typedef __attribute__((ext_vector_type(8))) short  short8;   // 8 bf16 (4 VGPR) MFMA A/B frag
typedef __attribute__((ext_vector_type(4))) short  short4_;  // 4 bf16 (8B)
typedef __attribute__((ext_vector_type(4))) float  float4_;  // MFMA C/D frag

__device__ __forceinline__ unsigned short f2bf(float f) {
  union { float f; unsigned int u; } v; v.f = f;
  unsigned int u = v.u;
  return (unsigned short)((u + 0x7FFFu + ((u >> 16) & 1u)) >> 16);  // RNE
}
__device__ __forceinline__ float bf2f(unsigned short u) {
  union { unsigned int i; float f; } v; v.i = ((unsigned int)u) << 16;
  return v.f;
}
// packed fp32x2 -> bf16x2
__device__ __forceinline__ void pk2(short4_& dst, int idx2, float a, float b) {
  union { __hip_bfloat162 h2; struct { short x, y; } s; } u;
  u.h2 = __float22bfloat162_rn(make_float2(a, b));
  dst[idx2 * 2]     = u.s.x;
  dst[idx2 * 2 + 1] = u.s.y;
}

// async global->LDS, 16B per lane.  HW dest = wave-uniform base + lane*16,
// so LDS offsets must be contiguous in thread order (they are: base + tid*16).
__device__ __forceinline__ void async_cp16(const unsigned short* g, unsigned short* l) {
  __builtin_amdgcn_global_load_lds((__attribute__((address_space(1))) void*)g,
                                   (__attribute__((address_space(3))) void*)l,
                                   16, 0, 0);
}

// ----------------------------- fused fp32->bf16 (all 3 inputs) + trig tables
// Blocks 0..12287: bf16 conversion.  Blocks 12288..12799: RoPE trig tables
// ct/st[t*64+d] = cos/sin((sp+t) * 10000^(-d/64)).  Accurate sinf/cosf live
// HERE (tiny register footprint -> inlined; round-2 lesson: outlined trig
// inside the fat GEMM caused a scratch-write storm).
__global__ __launch_bounds__(256) void cvt_all(const float* __restrict__ x,
                                               const float* __restrict__ wqkv,
                                               const float* __restrict__ wproj,
                                               const int* __restrict__ sp_ptr,
                                               unsigned short* __restrict__ out,
                                               float* __restrict__ ct,
                                               float* __restrict__ st) {
  if (blockIdx.x >= 12288) {
    int j = (blockIdx.x - 12288) * 256 + threadIdx.x;   // 0..131071
    int d = j & 63;
    const float L2F = -0.20762050593046013f;  // -log2(10000)/64
    float fr = exp2f((float)d * L2F);
    float ang = (float)(sp_ptr[0] + (j >> 6)) * fr;
    ct[j] = cosf(ang);
    st[j] = sinf(ang);
    return;
  }
  int i = (blockIdx.x * 256 + threadIdx.x) * 8;   // 0 .. 25165824-8
  const float* src; int off;
  if (i < 8388608)       { src = x;     off = i; }
  else if (i < 20971520) { src = wqkv;  off = i - 8388608; }
  else                   { src = wproj; off = i - 20971520; }
  const float4_* p = (const float4_*)(src + off);
  float4_ a = p[0], b = p[1];
  short8 o;
  o[0] = (short)f2bf(a[0]); o[1] = (short)f2bf(a[1]);
  o[2] = (short)f2bf(a[2]); o[3] = (short)f2bf(a[3]);
  o[4] = (short)f2bf(b[0]); o[5] = (short)f2bf(b[1]);
  o[6] = (short)f2bf(b[2]); o[7] = (short)f2bf(b[3]);
  *(short8*)(out + i) = o;
}

// ------------------------------------------------------- GEMM  C = A * B^T
// (frozen m97-structure 128x128 kernel — used for the projection GEMM)
template <bool F32OUT>
__global__ __launch_bounds__(256) void gemm_bt(const unsigned short* __restrict__ A,
                                               const unsigned short* __restrict__ Bm,
                                               void* __restrict__ Cout,
                                               int M, int N, int K) {
  __shared__ __align__(16) unsigned short As[128 * 64];
  __shared__ __align__(16) unsigned short Bs[128 * 64];
  const int tid  = threadIdx.x;
  const int lane = tid & 63;
  const int col16 = lane & 15, quad = lane >> 4;
  const int wave = tid >> 6;
  const int wm = wave >> 1, wn = wave & 1;
  const int m0 = blockIdx.y * 128, n0 = blockIdx.x * 128;

  float4_ acc[4][4] = {};

  #pragma unroll 1
  for (int k0 = 0; k0 < K; k0 += 64) {
    __syncthreads();
    #pragma unroll
    for (int i = 0; i < 4; ++i) {
      int P   = i * 256 + tid;
      int row = P >> 3;                    // tile row 0..127
      int kc  = (P & 7) ^ (row & 7);       // logical chunk for this phys slot
      async_cp16(A  + (size_t)(m0 + row) * K + k0 + kc * 8, As + P * 8);
      async_cp16(Bm + (size_t)(n0 + row) * K + k0 + kc * 8, Bs + P * 8);
    }
    __syncthreads();
    #pragma unroll
    for (int ks = 0; ks < 2; ++ks) {
      short8 af[4], bf[4];
      #pragma unroll
      for (int i = 0; i < 4; ++i) {
        int ra = wm * 64 + i * 16 + col16;
        int ca = ((ks * 4 + quad) ^ (ra & 7)) * 8;
        af[i] = *(const short8*)(As + ra * 64 + ca);
        int rb = wn * 64 + i * 16 + col16;
        int cb = ((ks * 4 + quad) ^ (rb & 7)) * 8;
        bf[i] = *(const short8*)(Bs + rb * 64 + cb);
      }
      #pragma unroll
      for (int i = 0; i < 4; ++i)
        #pragma unroll
        for (int j = 0; j < 4; ++j)
          acc[i][j] = __builtin_amdgcn_mfma_f32_16x16x32_bf16(af[i], bf[j], acc[i][j], 0, 0, 0);
    }
  }

  // epilogue: C/D layout col=lane&15 (n), row=quad*4+reg (m)
  #pragma unroll
  for (int i = 0; i < 4; ++i) {
    int mg = m0 + wm * 64 + i * 16 + quad * 4;
    #pragma unroll
    for (int j = 0; j < 4; ++j) {
      int ng = n0 + wn * 64 + j * 16 + col16;
      #pragma unroll
      for (int r = 0; r < 4; ++r) {
        if constexpr (F32OUT)
          ((float*)Cout)[(size_t)(mg + r) * N + ng] = acc[i][j][r];
        else
          ((unsigned short*)Cout)[(size_t)(mg + r) * N + ng] = f2bf(acc[i][j][r]);
      }
    }
  }
}

// ---------------------------------------- GEMM1 + fused RoPE/split/V-transpose
// ACCEPTED at VGPR 112 / ~138 us (rounds 4-7 + 11: four register-diet
// attempts all nulled — the RoPE-pair epilogue's acc live-range sets the
// floor).  Main loop = gemm_bt with the paired B-row mapping
// rb = wn*32+(j&1)*16+(j>>1)*64+c16, so acc[i][j]/acc[i][j+2] hold the RoPE
// pair (d, d+64) in the same lane.  Each 128-wide n-tile is one head of
// Q, K or V (block-uniform epilogue mode).
__global__ __launch_bounds__(256) void gemm_qkv(const unsigned short* __restrict__ A,
                                                const unsigned short* __restrict__ Bm,
                                                const float* __restrict__ ct,
                                                const float* __restrict__ st,
                                                unsigned short* __restrict__ q_r,
                                                unsigned short* __restrict__ k_r,
                                                unsigned short* __restrict__ v_t) {
  __shared__ __align__(16) unsigned short S[16384];  // As = S[0:8192), Bs = S[8192:16384)
  unsigned short* As = S;
  unsigned short* Bs = S + 8192;
  const int tid  = threadIdx.x;
  const int lane = tid & 63;
  const int col16 = lane & 15, quad = lane >> 4;
  const int wave = tid >> 6;
  const int wm = wave >> 1, wn = wave & 1;
  const int m0 = blockIdx.y * 128, n0 = blockIdx.x * 128;

  float4_ acc[4][4] = {};

  #pragma unroll 1
  for (int k0 = 0; k0 < C_; k0 += 64) {
    __syncthreads();
    #pragma unroll
    for (int i = 0; i < 4; ++i) {
      int P   = i * 256 + tid;
      int row = P >> 3;
      int kc  = (P & 7) ^ (row & 7);
      async_cp16(A  + (size_t)(m0 + row) * C_ + k0 + kc * 8, As + P * 8);
      async_cp16(Bm + (size_t)(n0 + row) * C_ + k0 + kc * 8, Bs + P * 8);
    }
    __syncthreads();
    #pragma unroll
    for (int ks = 0; ks < 2; ++ks) {
      short8 af[4], bf[4];
      #pragma unroll
      for (int i = 0; i < 4; ++i) {
        int ra = wm * 64 + i * 16 + col16;
        int ca = ((ks * 4 + quad) ^ (ra & 7)) * 8;
        af[i] = *(const short8*)(As + ra * 64 + ca);
        // paired mapping: j={0,1} -> d in [wn*32, wn*32+32); j={2,3} -> +64
        int rb = wn * 32 + (i & 1) * 16 + (i >> 1) * 64 + col16;
        int cb = ((ks * 4 + quad) ^ (rb & 7)) * 8;
        bf[i] = *(const short8*)(Bs + rb * 64 + cb);
      }
      #pragma unroll
      for (int i = 0; i < 4; ++i)
        #pragma unroll
        for (int j = 0; j < 4; ++j)
          acc[i][j] = __builtin_amdgcn_mfma_f32_16x16x32_bf16(af[i], bf[j], acc[i][j], 0, 0, 0);
    }
  }

  // -------- fused epilogue --------
  const int region = n0 >> 11;           // 0=Q, 1=K, 2=V
  const int h   = (n0 & 2047) >> 7;      // head
  const int b   = m0 >> 11;              // batch (BM=128 never straddles b)
  const int t0l = m0 & 2047;             // token base within batch
  const int bh  = b * H_ + h;

  if (region < 2) {
    // ---- phase A: pack acc pairs to bf16 (32 VGPRs); acc dies here.
    short4_ pq[4][2][2];
    #pragma unroll
    for (int i = 0; i < 4; ++i)
      #pragma unroll
      for (int jl = 0; jl < 2; ++jl) {
        pk2(pq[i][jl][0], 0, acc[i][jl][0],     acc[i][jl][1]);
        pk2(pq[i][jl][0], 1, acc[i][jl][2],     acc[i][jl][3]);
        pk2(pq[i][jl][1], 0, acc[i][jl + 2][0], acc[i][jl + 2][1]);
        pk2(pq[i][jl][1], 1, acc[i][jl + 2][2], acc[i][jl + 2][3]);
      }
    __builtin_amdgcn_sched_barrier(0);   // phase boundary

    // ---- phase B: RoPE from packed values + trig tables, store bf16.
    unsigned short* dst = region ? k_r : q_r;
    const float scl = region ? 1.0f : 0.1275174117f;  // Q: (1/sqrt(128))*log2(e)
    #pragma unroll
    for (int i = 0; i < 4; ++i) {
      int tl = t0l + wm * 64 + i * 16 + quad * 4;     // token (local to batch), +r below
      #pragma unroll
      for (int jl = 0; jl < 2; ++jl) {
        int d = wn * 32 + jl * 16 + col16;            // 0..63 (lo half)
        size_t ob = (size_t)(bh * T_ + tl) * D_ + d;
        int ti = tl * 64 + d;
        #pragma unroll
        for (int r = 0; r < 4; ++r) {
          float cs = ct[ti + r * 64], sn = st[ti + r * 64];
          float lo = bf2f((unsigned short)pq[i][jl][0][r]);
          float hi = bf2f((unsigned short)pq[i][jl][1][r]);
          dst[ob + (size_t)r * D_]      = f2bf((lo * cs - hi * sn) * scl);
          dst[ob + (size_t)r * D_ + 64] = f2bf((lo * sn + hi * cs) * scl);
        }
      }
    }
  } else {
    // ---- V: transpose via LDS (reuse S, 32 KB = exactly the 128x128 bf16 tile)
    __syncthreads();   // all waves done reading As/Bs from the main loop
    #pragma unroll
    for (int i = 0; i < 4; ++i) {
      int tlb = wm * 64 + i * 16 + quad * 4;          // local token 0..127
      #pragma unroll
      for (int j = 0; j < 4; ++j) {
        int d = wn * 32 + (j & 1) * 16 + (j >> 1) * 64 + col16;
        #pragma unroll
        for (int r = 0; r < 4; ++r) {
          int t = tlb + r;
          int ch = (t >> 3) ^ (d & 15);               // chunk swizzle (~2-way)
          S[d * 128 + ch * 8 + (t & 7)] = f2bf(acc[i][j][r]);
        }
      }
    }
    __syncthreads();
    // coalesced write: 2 threads per d-row, 128 B each
    int drow = tid >> 1, hf = tid & 1;
    size_t gb = (size_t)(bh * D_ + drow) * T_ + t0l + hf * 64;
    #pragma unroll
    for (int cc = 0; cc < 8; ++cc) {
      int ch = (hf * 8 + cc) ^ (drow & 15);
      *(short8*)(v_t + gb + cc * 8) = *(const short8*)(S + drow * 128 + ch * 8);
    }
  }
}

// ------------------------------------------------------- flash attention v7
// v4 structure (best measured) + fixed-serial-cost cuts on the per-tile
// critical chain (r8 calibration: ~1.5us/tile-body -> dominated by the
// 4 shfl LDS-latency ops + rescale, not instruction throughput [r9 null]):
// (a) per-lane PARTIAL l: l is linear, so accumulate per-lane and reduce
//     ONCE after the kv loop (2 shfls total, not 2 per tile).
// (b) defer-max with LANE-LOCAL test: __all(rm_local <= m_i + 11.5) uses
//     the SALU ballot as the cross-lane reduce -> common path has ZERO
//     shuffles and ZERO oacc rescale.  Rescale path (max actually grew:
//     first tile, then rare) does the full rm reduce + alpha rescale of
//     oacc and the l partial.  P bounded by 2^11.5 — safe in f32.
// (c) s_setprio(1) around both MFMA clusters (T5: attn +4-7%, m191).
// Grid 512 (16 qt x 32 bh), qt=(g<8?g:23-g) pairing, 512 thr, 2 blocks/CU.
__global__ __launch_bounds__(512, 4) void attn_fwd(const unsigned short* __restrict__ q_r,
                                                   const unsigned short* __restrict__ k_r,
                                                   const unsigned short* __restrict__ v_t,
                                                   unsigned short* __restrict__ Ob) {
  __shared__ __align__(16) unsigned short Ks[2][64 * 128];   // [s][d] swizzled, dbuf
  __shared__ __align__(16) unsigned short Vts[2][128 * 64];  // [d][s] swizzled, dbuf
  __shared__ __align__(16) unsigned short Ps[128 * 64];      // [qrow][s] swizzled
  const int g     = blockIdx.x >> 5;   // 0..15
  const int bh    = blockIdx.x & 31;   // low bits -> XCD locality by head
  const int qt    = (g < 8) ? g : 23 - g;   // balanced co-residency pairing
  const int tid  = threadIdx.x;
  const int lane = tid & 63;
  const int col16 = lane & 15, quad = lane >> 4;
  const int wave = tid >> 6;           // 0..7
  const float NEG_INF = -__builtin_inff();
  const int b = bh >> 4, h = bh & 15;
  const int qlr = wave * 16 + col16;   // this lane's q row within the 128-tile

  const int q0 = qt * 128;
  const int njt = 2 * qt + 2;                   // 64-row kv tiles

  // Q frags (B-operand): B[k=d][n=qrow], 8 contiguous d per lane (pre-scaled)
  short8 qf[4];
  const unsigned short* qp = q_r + (size_t)(bh * T_ + q0 + qlr) * D_;
  #pragma unroll
  for (int ks = 0; ks < 4; ++ks) qf[ks] = *(const short8*)(qp + ks * 32 + quad * 8);

  float4_ oacc[8] = {};
  float m_i = NEG_INF, l_lane = 0.f;   // l kept as PER-LANE partial (reduced once at end)

  const unsigned short* kbase = k_r + (size_t)bh * T_ * D_;
  const unsigned short* vbase = v_t + (size_t)bh * D_ * T_;
  #define STAGE(JT, BUF)                                                        \
    {                                                                           \
      const unsigned short* kb = kbase + (size_t)(JT) * 64 * D_;                \
      const unsigned short* vb = vbase + (size_t)(JT) * 64;                     \
      unsigned short* kd = &Ks[(BUF)][0];                                       \
      unsigned short* vd = &Vts[(BUF)][0];                                      \
      _Pragma("unroll")                                                         \
      for (int i = 0; i < 2; ++i) {                                             \
        int P = i * 512 + tid;                                                  \
        int krow = P >> 4, kc = (P & 15) ^ (krow & 7);                          \
        async_cp16(kb + krow * D_ + kc * 8, kd + P * 8);                        \
        int vrow = P >> 3, vc = (P & 7) ^ (vrow & 7);                           \
        async_cp16(vb + (size_t)vrow * T_ + vc * 8, vd + P * 8);                \
      }                                                                         \
    }

  STAGE(0, 0);

  #pragma unroll 1
  for (int jt = 0; jt < njt; ++jt) {
    __syncthreads();                    // tile jt landed; prior reads done
    if (jt + 1 < njt) STAGE(jt + 1, (jt + 1) & 1);

    // wave-uniform skip: this wave's 16 q-rows all above (before) this kv tile
    if (jt * 64 > q0 + wave * 16 + 15) continue;

    const unsigned short* KsB  = &Ks[jt & 1][0];
    const unsigned short* VtsB = &Vts[jt & 1][0];

    // S^T tiles: A = K rows, B = Q  (values already in log2-softmax domain)
    float4_ s[4];
    __builtin_amdgcn_s_setprio(1);
    #pragma unroll
    for (int jn = 0; jn < 4; ++jn) {
      float4_ a = {};
      #pragma unroll
      for (int ks = 0; ks < 4; ++ks) {
        int kr = jn * 16 + col16;
        int ch = ((ks * 4 + quad) ^ (kr & 7)) * 8;
        short8 kfr = *(const short8*)(KsB + kr * 128 + ch);
        a = __builtin_amdgcn_mfma_f32_16x16x32_bf16(kfr, qf[ks], a, 0, 0, 0);
      }
      s[jn] = a;
    }
    __builtin_amdgcn_s_setprio(0);
    if (jt * 64 + 63 > q0 + wave * 16) {  // wave-uniform partial-mask branch
      #pragma unroll
      for (int jn = 0; jn < 4; ++jn)
        #pragma unroll
        for (int r = 0; r < 4; ++r)
          if (jt * 64 + jn * 16 + quad * 4 + r > q0 + qlr) s[jn][r] = NEG_INF;
    }
    // ---- online softmax, log2 domain, defer-max form ----
    // lane-local max of this tile's 16 values
    float rmloc = NEG_INF;
    #pragma unroll
    for (int jn = 0; jn < 4; ++jn)
      #pragma unroll
      for (int r = 0; r < 4; ++r) rmloc = fmaxf(rmloc, s[jn][r]);
    // common path (max didn't grow by >11.5 = ln-domain 8): no shuffles,
    // no rescale.  SALU ballot is the implicit cross-lane reduce.
    if (!__all(rmloc <= m_i + 11.5f)) {
      float rm = fmaxf(rmloc, __shfl_xor(rmloc, 16));
      rm = fmaxf(rm, __shfl_xor(rm, 32));
      float m_new = fmaxf(m_i, rm);
      float alpha = exp2f(m_i - m_new);   // m_i=-inf (first tile) -> alpha=0
      l_lane *= alpha;
      #pragma unroll
      for (int dt = 0; dt < 8; ++dt) oacc[dt] *= alpha;
      m_i = m_new;
    }
    float rs = 0.f;
    #pragma unroll
    for (int jn = 0; jn < 4; ++jn)
      #pragma unroll
      for (int r = 0; r < 4; ++r) {
        float pv = exp2f(s[jn][r] - m_i);
        s[jn][r] = pv;
        rs += pv;
      }
    l_lane += rs;

    // P -> LDS (wave-private rows), packed bf16
    #pragma unroll
    for (int jn = 0; jn < 4; ++jn) {
      short4_ pkv;
      pk2(pkv, 0, s[jn][0], s[jn][1]);
      pk2(pkv, 1, s[jn][2], s[jn][3]);
      int c0 = jn * 16 + quad * 4;
      int ch = (c0 >> 3) ^ (qlr & 7);
      *(short4_*)(Ps + qlr * 64 + ch * 8 + (c0 & 7)) = pkv;
    }
    __builtin_amdgcn_s_waitcnt(0xC07F);  // lgkmcnt(0): own P writes -> own reads

    // O^T += V^T · P^T : A = Vts (m=d), B = Ps rows (n=qrow)
    short8 pf[2];
    #pragma unroll
    for (int ks2 = 0; ks2 < 2; ++ks2) {
      int ch = ((ks2 * 4 + quad) ^ (qlr & 7)) * 8;
      pf[ks2] = *(const short8*)(Ps + qlr * 64 + ch);
    }
    __builtin_amdgcn_s_setprio(1);
    #pragma unroll
    for (int dt = 0; dt < 8; ++dt)
      #pragma unroll
      for (int ks2 = 0; ks2 < 2; ++ks2) {
        int vr = dt * 16 + col16;
        int ch = ((ks2 * 4 + quad) ^ (vr & 7)) * 8;
        short8 vf = *(const short8*)(VtsB + vr * 64 + ch);
        oacc[dt] = __builtin_amdgcn_mfma_f32_16x16x32_bf16(vf, pf[ks2], oacc[dt], 0, 0, 0);
      }
    __builtin_amdgcn_s_setprio(0);
  }

  // one-time l reduction: the 4 lanes {l, l+16, l+32, l+48} share a q-row
  float lt = l_lane + __shfl_xor(l_lane, 16);
  lt += __shfl_xor(lt, 32);

  // epilogue: O^T C-layout col=lane&15=qrow, row=quad*4+r=d
  float inv_l = 1.0f / lt;
  size_t ob = (size_t)(b * T_ + q0 + qlr) * C_ + h * D_;
  #pragma unroll
  for (int dt = 0; dt < 8; ++dt) {
    short4_ o4;
    pk2(o4, 0, oacc[dt][0] * inv_l, oacc[dt][1] * inv_l);
    pk2(o4, 1, oacc[dt][2] * inv_l, oacc[dt][3] * inv_l);
    *(short4_*)(Ob + ob + dt * 16 + quad * 4) = o4;
  }
  #undef STAGE
}

// ---------------------------------------------------------------- launcher
extern "C" void kernel_launch(void* const* d_in, const int* in_sizes, int n_in,
                              void* d_out, int out_size, void* d_ws, size_t ws_size,
                              hipStream_t stream) {
  const float* x     = (const float*)d_in[0];
  const float* Wqkv  = (const float*)d_in[1];
  const float* Wproj = (const float*)d_in[2];
  const int*   sp    = (const int*)d_in[3];
  float* out = (float*)d_out;

  unsigned short* ws     = (unsigned short*)d_ws;
  unsigned short* xb     = ws;                    //  8,388,608
  unsigned short* wqkvb  = xb + 8388608;          // 12,582,912
  unsigned short* wprojb = wqkvb + 12582912;      //  4,194,304
  unsigned short* q_r    = wprojb + 4194304;      //  8,388,608
  unsigned short* k_r    = q_r + 8388608;         //  8,388,608
  unsigned short* v_t    = k_r + 8388608;         //  8,388,608
  float*          ctab   = (float*)(v_t + 8388608);  // 131,072 f32
  float*          stab   = ctab + 131072;            // 131,072 f32
  unsigned short* Obuf   = xb;                    // alias: xb dead after GEMM1

  // bf16 conversion + trig tables in one launch (trig blocks at the tail)
  cvt_all<<<12800, 256, 0, stream>>>(x, Wqkv, Wproj, sp, ws, ctab, stab);

  // QKV projection with fused RoPE/split/V-transpose
  gemm_qkv<<<dim3(48, 32), 256, 0, stream>>>(xb, wqkvb, ctab, stab, q_r, k_r, v_t);

  // attention v7: defer-max + per-lane l partial + setprio
  attn_fwd<<<dim3(512), 512, 0, stream>>>(q_r, k_r, v_t, Obuf);

  gemm_bt<true><<<dim3(16, 32), 256, 0, stream>>>(Obuf, wprojb, (void*)out, BT_, C_, C_);
}

// Round 13
// 362.331 us; speedup vs baseline: 1.0961x; 1.0022x over previous
//
#include <hip/hip_runtime.h>
#include <hip/hip_bf16.h>
#include <stdint.h>
#include <math.h>

// Problem constants
#define B_    2
#define T_    2048
#define C_    2048
#define H_    16
#define D_    128
#define NQKV  6144      // 3*C
#define BT_   4096      // B*T

typedef __attribute__((ext_vector_type(8))) short  short8;   // 8 bf16 (4 VGPR) MFMA A/B frag
typedef __attribute__((ext_vector_type(4))) short  short4_;  // 4 bf16 (8B)
typedef __attribute__((ext_vector_type(4))) float  float4_;  // MFMA C/D frag

__device__ __forceinline__ unsigned short f2bf(float f) {
  union { float f; unsigned int u; } v; v.f = f;
  unsigned int u = v.u;
  return (unsigned short)((u + 0x7FFFu + ((u >> 16) & 1u)) >> 16);  // RNE
}
__device__ __forceinline__ float bf2f(unsigned short u) {
  union { unsigned int i; float f; } v; v.i = ((unsigned int)u) << 16;
  return v.f;
}
// packed fp32x2 -> bf16x2
__device__ __forceinline__ void pk2(short4_& dst, int idx2, float a, float b) {
  union { __hip_bfloat162 h2; struct { short x, y; } s; } u;
  u.h2 = __float22bfloat162_rn(make_float2(a, b));
  dst[idx2 * 2]     = u.s.x;
  dst[idx2 * 2 + 1] = u.s.y;
}

// async global->LDS, 16B per lane.  HW dest = wave-uniform base + lane*16,
// so LDS offsets must be contiguous in thread order (they are: base + tid*16).
__device__ __forceinline__ void async_cp16(const unsigned short* g, unsigned short* l) {
  __builtin_amdgcn_global_load_lds((__attribute__((address_space(1))) void*)g,
                                   (__attribute__((address_space(3))) void*)l,
                                   16, 0, 0);
}

// ----------------------------- fused fp32->bf16 (all 3 inputs) + trig tables
// Blocks 0..12287: bf16 conversion.  Blocks 12288..12799: RoPE trig tables
// ct/st[t*64+d] = cos/sin((sp+t) * 10000^(-d/64)).  Accurate sinf/cosf live
// HERE (tiny register footprint -> inlined; round-2 lesson: outlined trig
// inside the fat GEMM caused a scratch-write storm).
__global__ __launch_bounds__(256) void cvt_all(const float* __restrict__ x,
                                               const float* __restrict__ wqkv,
                                               const float* __restrict__ wproj,
                                               const int* __restrict__ sp_ptr,
                                               unsigned short* __restrict__ out,
                                               float* __restrict__ ct,
                                               float* __restrict__ st) {
  if (blockIdx.x >= 12288) {
    int j = (blockIdx.x - 12288) * 256 + threadIdx.x;   // 0..131071
    int d = j & 63;
    const float L2F = -0.20762050593046013f;  // -log2(10000)/64
    float fr = exp2f((float)d * L2F);
    float ang = (float)(sp_ptr[0] + (j >> 6)) * fr;
    ct[j] = cosf(ang);
    st[j] = sinf(ang);
    return;
  }
  int i = (blockIdx.x * 256 + threadIdx.x) * 8;   // 0 .. 25165824-8
  const float* src; int off;
  if (i < 8388608)       { src = x;     off = i; }
  else if (i < 20971520) { src = wqkv;  off = i - 8388608; }
  else                   { src = wproj; off = i - 20971520; }
  const float4_* p = (const float4_*)(src + off);
  float4_ a = p[0], b = p[1];
  short8 o;
  o[0] = (short)f2bf(a[0]); o[1] = (short)f2bf(a[1]);
  o[2] = (short)f2bf(a[2]); o[3] = (short)f2bf(a[3]);
  o[4] = (short)f2bf(b[0]); o[5] = (short)f2bf(b[1]);
  o[6] = (short)f2bf(b[2]); o[7] = (short)f2bf(b[3]);
  *(short8*)(out + i) = o;
}

// ------------------------------------------------------- GEMM  C = A * B^T
// (frozen m97-structure 128x128 kernel — used for the projection GEMM)
template <bool F32OUT>
__global__ __launch_bounds__(256) void gemm_bt(const unsigned short* __restrict__ A,
                                               const unsigned short* __restrict__ Bm,
                                               void* __restrict__ Cout,
                                               int M, int N, int K) {
  __shared__ __align__(16) unsigned short As[128 * 64];
  __shared__ __align__(16) unsigned short Bs[128 * 64];
  const int tid  = threadIdx.x;
  const int lane = tid & 63;
  const int col16 = lane & 15, quad = lane >> 4;
  const int wave = tid >> 6;
  const int wm = wave >> 1, wn = wave & 1;
  const int m0 = blockIdx.y * 128, n0 = blockIdx.x * 128;

  float4_ acc[4][4] = {};

  #pragma unroll 1
  for (int k0 = 0; k0 < K; k0 += 64) {
    __syncthreads();
    #pragma unroll
    for (int i = 0; i < 4; ++i) {
      int P   = i * 256 + tid;
      int row = P >> 3;                    // tile row 0..127
      int kc  = (P & 7) ^ (row & 7);       // logical chunk for this phys slot
      async_cp16(A  + (size_t)(m0 + row) * K + k0 + kc * 8, As + P * 8);
      async_cp16(Bm + (size_t)(n0 + row) * K + k0 + kc * 8, Bs + P * 8);
    }
    __syncthreads();
    #pragma unroll
    for (int ks = 0; ks < 2; ++ks) {
      short8 af[4], bf[4];
      #pragma unroll
      for (int i = 0; i < 4; ++i) {
        int ra = wm * 64 + i * 16 + col16;
        int ca = ((ks * 4 + quad) ^ (ra & 7)) * 8;
        af[i] = *(const short8*)(As + ra * 64 + ca);
        int rb = wn * 64 + i * 16 + col16;
        int cb = ((ks * 4 + quad) ^ (rb & 7)) * 8;
        bf[i] = *(const short8*)(Bs + rb * 64 + cb);
      }
      #pragma unroll
      for (int i = 0; i < 4; ++i)
        #pragma unroll
        for (int j = 0; j < 4; ++j)
          acc[i][j] = __builtin_amdgcn_mfma_f32_16x16x32_bf16(af[i], bf[j], acc[i][j], 0, 0, 0);
    }
  }

  // epilogue: C/D layout col=lane&15 (n), row=quad*4+reg (m)
  #pragma unroll
  for (int i = 0; i < 4; ++i) {
    int mg = m0 + wm * 64 + i * 16 + quad * 4;
    #pragma unroll
    for (int j = 0; j < 4; ++j) {
      int ng = n0 + wn * 64 + j * 16 + col16;
      #pragma unroll
      for (int r = 0; r < 4; ++r) {
        if constexpr (F32OUT)
          ((float*)Cout)[(size_t)(mg + r) * N + ng] = acc[i][j][r];
        else
          ((unsigned short*)Cout)[(size_t)(mg + r) * N + ng] = f2bf(acc[i][j][r]);
      }
    }
  }
}

// ---------------------------------------- GEMM1 + fused RoPE/split/V-transpose
// ACCEPTED at VGPR 112 / ~138 us (rounds 4-7 + 11: four register-diet
// attempts all nulled — the RoPE-pair epilogue's acc live-range sets the
// floor).  Main loop = gemm_bt with the paired B-row mapping
// rb = wn*32+(j&1)*16+(j>>1)*64+c16, so acc[i][j]/acc[i][j+2] hold the RoPE
// pair (d, d+64) in the same lane.  Each 128-wide n-tile is one head of
// Q, K or V (block-uniform epilogue mode).
__global__ __launch_bounds__(256) void gemm_qkv(const unsigned short* __restrict__ A,
                                                const unsigned short* __restrict__ Bm,
                                                const float* __restrict__ ct,
                                                const float* __restrict__ st,
                                                unsigned short* __restrict__ q_r,
                                                unsigned short* __restrict__ k_r,
                                                unsigned short* __restrict__ v_t) {
  __shared__ __align__(16) unsigned short S[16384];  // As = S[0:8192), Bs = S[8192:16384)
  unsigned short* As = S;
  unsigned short* Bs = S + 8192;
  const int tid  = threadIdx.x;
  const int lane = tid & 63;
  const int col16 = lane & 15, quad = lane >> 4;
  const int wave = tid >> 6;
  const int wm = wave >> 1, wn = wave & 1;
  const int m0 = blockIdx.y * 128, n0 = blockIdx.x * 128;

  float4_ acc[4][4] = {};

  #pragma unroll 1
  for (int k0 = 0; k0 < C_; k0 += 64) {
    __syncthreads();
    #pragma unroll
    for (int i = 0; i < 4; ++i) {
      int P   = i * 256 + tid;
      int row = P >> 3;
      int kc  = (P & 7) ^ (row & 7);
      async_cp16(A  + (size_t)(m0 + row) * C_ + k0 + kc * 8, As + P * 8);
      async_cp16(Bm + (size_t)(n0 + row) * C_ + k0 + kc * 8, Bs + P * 8);
    }
    __syncthreads();
    #pragma unroll
    for (int ks = 0; ks < 2; ++ks) {
      short8 af[4], bf[4];
      #pragma unroll
      for (int i = 0; i < 4; ++i) {
        int ra = wm * 64 + i * 16 + col16;
        int ca = ((ks * 4 + quad) ^ (ra & 7)) * 8;
        af[i] = *(const short8*)(As + ra * 64 + ca);
        // paired mapping: j={0,1} -> d in [wn*32, wn*32+32); j={2,3} -> +64
        int rb = wn * 32 + (i & 1) * 16 + (i >> 1) * 64 + col16;
        int cb = ((ks * 4 + quad) ^ (rb & 7)) * 8;
        bf[i] = *(const short8*)(Bs + rb * 64 + cb);
      }
      #pragma unroll
      for (int i = 0; i < 4; ++i)
        #pragma unroll
        for (int j = 0; j < 4; ++j)
          acc[i][j] = __builtin_amdgcn_mfma_f32_16x16x32_bf16(af[i], bf[j], acc[i][j], 0, 0, 0);
    }
  }

  // -------- fused epilogue --------
  const int region = n0 >> 11;           // 0=Q, 1=K, 2=V
  const int h   = (n0 & 2047) >> 7;      // head
  const int b   = m0 >> 11;              // batch (BM=128 never straddles b)
  const int t0l = m0 & 2047;             // token base within batch
  const int bh  = b * H_ + h;

  if (region < 2) {
    // ---- phase A: pack acc pairs to bf16 (32 VGPRs); acc dies here.
    short4_ pq[4][2][2];
    #pragma unroll
    for (int i = 0; i < 4; ++i)
      #pragma unroll
      for (int jl = 0; jl < 2; ++jl) {
        pk2(pq[i][jl][0], 0, acc[i][jl][0],     acc[i][jl][1]);
        pk2(pq[i][jl][0], 1, acc[i][jl][2],     acc[i][jl][3]);
        pk2(pq[i][jl][1], 0, acc[i][jl + 2][0], acc[i][jl + 2][1]);
        pk2(pq[i][jl][1], 1, acc[i][jl + 2][2], acc[i][jl + 2][3]);
      }
    __builtin_amdgcn_sched_barrier(0);   // phase boundary

    // ---- phase B: RoPE from packed values + trig tables, store bf16.
    unsigned short* dst = region ? k_r : q_r;
    const float scl = region ? 1.0f : 0.1275174117f;  // Q: (1/sqrt(128))*log2(e)
    #pragma unroll
    for (int i = 0; i < 4; ++i) {
      int tl = t0l + wm * 64 + i * 16 + quad * 4;     // token (local to batch), +r below
      #pragma unroll
      for (int jl = 0; jl < 2; ++jl) {
        int d = wn * 32 + jl * 16 + col16;            // 0..63 (lo half)
        size_t ob = (size_t)(bh * T_ + tl) * D_ + d;
        int ti = tl * 64 + d;
        #pragma unroll
        for (int r = 0; r < 4; ++r) {
          float cs = ct[ti + r * 64], sn = st[ti + r * 64];
          float lo = bf2f((unsigned short)pq[i][jl][0][r]);
          float hi = bf2f((unsigned short)pq[i][jl][1][r]);
          dst[ob + (size_t)r * D_]      = f2bf((lo * cs - hi * sn) * scl);
          dst[ob + (size_t)r * D_ + 64] = f2bf((lo * sn + hi * cs) * scl);
        }
      }
    }
  } else {
    // ---- V: transpose via LDS (reuse S, 32 KB = exactly the 128x128 bf16 tile)
    __syncthreads();   // all waves done reading As/Bs from the main loop
    #pragma unroll
    for (int i = 0; i < 4; ++i) {
      int tlb = wm * 64 + i * 16 + quad * 4;          // local token 0..127
      #pragma unroll
      for (int j = 0; j < 4; ++j) {
        int d = wn * 32 + (j & 1) * 16 + (j >> 1) * 64 + col16;
        #pragma unroll
        for (int r = 0; r < 4; ++r) {
          int t = tlb + r;
          int ch = (t >> 3) ^ (d & 15);               // chunk swizzle (~2-way)
          S[d * 128 + ch * 8 + (t & 7)] = f2bf(acc[i][j][r]);
        }
      }
    }
    __syncthreads();
    // coalesced write: 2 threads per d-row, 128 B each
    int drow = tid >> 1, hf = tid & 1;
    size_t gb = (size_t)(bh * D_ + drow) * T_ + t0l + hf * 64;
    #pragma unroll
    for (int cc = 0; cc < 8; ++cc) {
      int ch = (hf * 8 + cc) ^ (drow & 15);
      *(short8*)(v_t + gb + cc * 8) = *(const short8*)(S + drow * 128 + ch * 8);
    }
  }
}

// ------------------------------------------------------- flash attention v8
// v7 + KVBLK 64 -> 128: HALVE the number of tile bodies.  Elimination table
// (r8: co-residency null ±3us; r9: 0.58x LDS-ops/0.5x MFMA null; r12:
// softmax-chain cut +4us) leaves a per-tile FIXED cost (barrier + gload_lds
// drain + mask/bookkeeping) as the dominant attn term.  Fewer, bigger tiles
// attack it directly: 272 -> 136 tiles per bh-pair.  LDS = K 2x32 + V 2x32
// + Ps 32 = 160 KB (full CU) -> 1 block/CU; grid 512 (16 qt x 32 bh) with
// qt=(g<8?g:23-g) so the two sequential rounds per CU sum to uniform 17
// 128-row tiles.  All v7 wins retained (defer-max ballot, per-lane l
// partial, setprio).  Swizzles: K rows unchanged (were already 128 wide);
// V/Ps rows widen to 16 chunks with the same XOR family.
__global__ __launch_bounds__(512) void attn_fwd(const unsigned short* __restrict__ q_r,
                                                const unsigned short* __restrict__ k_r,
                                                const unsigned short* __restrict__ v_t,
                                                unsigned short* __restrict__ Ob) {
  __shared__ __align__(16) unsigned short Ks[2][128 * 128];   // [s][d] swizzled, dbuf
  __shared__ __align__(16) unsigned short Vts[2][128 * 128];  // [d][s] swizzled, dbuf
  __shared__ __align__(16) unsigned short Ps[128 * 128];      // [qrow][s] swizzled
  const int g     = blockIdx.x >> 5;   // 0..15
  const int bh    = blockIdx.x & 31;   // low bits -> XCD locality by head
  const int qt    = (g < 8) ? g : 23 - g;   // balanced round pairing (sum 15)
  const int tid  = threadIdx.x;
  const int lane = tid & 63;
  const int col16 = lane & 15, quad = lane >> 4;
  const int wave = tid >> 6;           // 0..7
  const float NEG_INF = -__builtin_inff();
  const int b = bh >> 4, h = bh & 15;
  const int qlr = wave * 16 + col16;   // this lane's q row within the 128-tile

  const int q0 = qt * 128;
  const int njt = qt + 1;              // 128-row kv tiles

  // Q frags (B-operand): B[k=d][n=qrow], 8 contiguous d per lane (pre-scaled)
  short8 qf[4];
  const unsigned short* qp = q_r + (size_t)(bh * T_ + q0 + qlr) * D_;
  #pragma unroll
  for (int ks = 0; ks < 4; ++ks) qf[ks] = *(const short8*)(qp + ks * 32 + quad * 8);

  float4_ oacc[8] = {};
  float m_i = NEG_INF, l_lane = 0.f;   // l kept as PER-LANE partial

  const unsigned short* kbase = k_r + (size_t)bh * T_ * D_;
  const unsigned short* vbase = v_t + (size_t)bh * D_ * T_;
  // stage one 128-row K tile (32 KB) + one 128-col V tile (32 KB):
  // 2048 chunks each, 512 threads x 4 iters
  #define STAGE(JT, BUF)                                                        \
    {                                                                           \
      const unsigned short* kb = kbase + (size_t)(JT) * 128 * D_;               \
      const unsigned short* vb = vbase + (size_t)(JT) * 128;                    \
      unsigned short* kd = &Ks[(BUF)][0];                                       \
      unsigned short* vd = &Vts[(BUF)][0];                                      \
      _Pragma("unroll")                                                         \
      for (int i = 0; i < 4; ++i) {                                             \
        int P = i * 512 + tid;                                                  \
        int krow = P >> 4, kc = (P & 15) ^ (krow & 7);                          \
        async_cp16(kb + krow * D_ + kc * 8, kd + P * 8);                        \
        int vrow = P >> 4, vc = (P & 15) ^ (vrow & 7);                          \
        async_cp16(vb + (size_t)vrow * T_ + vc * 8, vd + P * 8);                \
      }                                                                         \
    }

  STAGE(0, 0);

  #pragma unroll 1
  for (int jt = 0; jt < njt; ++jt) {
    __syncthreads();                    // tile jt landed; prior reads done
    if (jt + 1 < njt) STAGE(jt + 1, (jt + 1) & 1);

    const unsigned short* KsB  = &Ks[jt & 1][0];
    const unsigned short* VtsB = &Vts[jt & 1][0];

    // S^T tiles: A = K rows, B = Q  (values already in log2-softmax domain)
    float4_ s[8];
    __builtin_amdgcn_s_setprio(1);
    #pragma unroll
    for (int jn = 0; jn < 8; ++jn) {
      float4_ a = {};
      #pragma unroll
      for (int ks = 0; ks < 4; ++ks) {
        int kr = jn * 16 + col16;
        int ch = ((ks * 4 + quad) ^ (kr & 7)) * 8;
        short8 kfr = *(const short8*)(KsB + kr * 128 + ch);
        a = __builtin_amdgcn_mfma_f32_16x16x32_bf16(kfr, qf[ks], a, 0, 0, 0);
      }
      s[jn] = a;
    }
    __builtin_amdgcn_s_setprio(0);
    if (jt * 128 + 127 > q0 + wave * 16) {  // wave-uniform partial-mask branch
      #pragma unroll
      for (int jn = 0; jn < 8; ++jn)
        #pragma unroll
        for (int r = 0; r < 4; ++r)
          if (jt * 128 + jn * 16 + quad * 4 + r > q0 + qlr) s[jn][r] = NEG_INF;
    }
    // ---- online softmax, log2 domain, defer-max form (v7) ----
    float rmloc = NEG_INF;
    #pragma unroll
    for (int jn = 0; jn < 8; ++jn)
      #pragma unroll
      for (int r = 0; r < 4; ++r) rmloc = fmaxf(rmloc, s[jn][r]);
    if (!__all(rmloc <= m_i + 11.5f)) {
      float rm = fmaxf(rmloc, __shfl_xor(rmloc, 16));
      rm = fmaxf(rm, __shfl_xor(rm, 32));
      float m_new = fmaxf(m_i, rm);
      float alpha = exp2f(m_i - m_new);   // m_i=-inf (first tile) -> alpha=0
      l_lane *= alpha;
      #pragma unroll
      for (int dt = 0; dt < 8; ++dt) oacc[dt] *= alpha;
      m_i = m_new;
    }
    float rs = 0.f;
    #pragma unroll
    for (int jn = 0; jn < 8; ++jn)
      #pragma unroll
      for (int r = 0; r < 4; ++r) {
        float pv = exp2f(s[jn][r] - m_i);
        s[jn][r] = pv;
        rs += pv;
      }
    l_lane += rs;

    // P -> LDS (wave-private rows), packed bf16; 16-chunk rows
    #pragma unroll
    for (int jn = 0; jn < 8; ++jn) {
      short4_ pkv;
      pk2(pkv, 0, s[jn][0], s[jn][1]);
      pk2(pkv, 1, s[jn][2], s[jn][3]);
      int c0 = jn * 16 + quad * 4;                    // 0..127
      int ch = (c0 >> 3) ^ (qlr & 7);
      *(short4_*)(Ps + qlr * 128 + ch * 8 + (c0 & 7)) = pkv;
    }
    __builtin_amdgcn_s_waitcnt(0xC07F);  // lgkmcnt(0): own P writes -> own reads

    // O^T += V^T · P^T : A = Vts (m=d), B = Ps rows (n=qrow)
    short8 pf[4];
    #pragma unroll
    for (int ks2 = 0; ks2 < 4; ++ks2) {
      int ch = ((ks2 * 4 + quad) ^ (qlr & 7)) * 8;
      pf[ks2] = *(const short8*)(Ps + qlr * 128 + ch);
    }
    __builtin_amdgcn_s_setprio(1);
    #pragma unroll
    for (int dt = 0; dt < 8; ++dt)
      #pragma unroll
      for (int ks2 = 0; ks2 < 4; ++ks2) {
        int vr = dt * 16 + col16;
        int ch = ((ks2 * 4 + quad) ^ (vr & 7)) * 8;
        short8 vf = *(const short8*)(VtsB + vr * 128 + ch);
        oacc[dt] = __builtin_amdgcn_mfma_f32_16x16x32_bf16(vf, pf[ks2], oacc[dt], 0, 0, 0);
      }
    __builtin_amdgcn_s_setprio(0);
  }

  // one-time l reduction: the 4 lanes {l, l+16, l+32, l+48} share a q-row
  float lt = l_lane + __shfl_xor(l_lane, 16);
  lt += __shfl_xor(lt, 32);

  // epilogue: O^T C-layout col=lane&15=qrow, row=quad*4+r=d
  float inv_l = 1.0f / lt;
  size_t ob = (size_t)(b * T_ + q0 + qlr) * C_ + h * D_;
  #pragma unroll
  for (int dt = 0; dt < 8; ++dt) {
    short4_ o4;
    pk2(o4, 0, oacc[dt][0] * inv_l, oacc[dt][1] * inv_l);
    pk2(o4, 1, oacc[dt][2] * inv_l, oacc[dt][3] * inv_l);
    *(short4_*)(Ob + ob + dt * 16 + quad * 4) = o4;
  }
  #undef STAGE
}

// ---------------------------------------------------------------- launcher
extern "C" void kernel_launch(void* const* d_in, const int* in_sizes, int n_in,
                              void* d_out, int out_size, void* d_ws, size_t ws_size,
                              hipStream_t stream) {
  const float* x     = (const float*)d_in[0];
  const float* Wqkv  = (const float*)d_in[1];
  const float* Wproj = (const float*)d_in[2];
  const int*   sp    = (const int*)d_in[3];
  float* out = (float*)d_out;

  unsigned short* ws     = (unsigned short*)d_ws;
  unsigned short* xb     = ws;                    //  8,388,608
  unsigned short* wqkvb  = xb + 8388608;          // 12,582,912
  unsigned short* wprojb = wqkvb + 12582912;      //  4,194,304
  unsigned short* q_r    = wprojb + 4194304;      //  8,388,608
  unsigned short* k_r    = q_r + 8388608;         //  8,388,608
  unsigned short* v_t    = k_r + 8388608;         //  8,388,608
  float*          ctab   = (float*)(v_t + 8388608);  // 131,072 f32
  float*          stab   = ctab + 131072;            // 131,072 f32
  unsigned short* Obuf   = xb;                    // alias: xb dead after GEMM1

  // bf16 conversion + trig tables in one launch (trig blocks at the tail)
  cvt_all<<<12800, 256, 0, stream>>>(x, Wqkv, Wproj, sp, ws, ctab, stab);

  // QKV projection with fused RoPE/split/V-transpose
  gemm_qkv<<<dim3(48, 32), 256, 0, stream>>>(xb, wqkvb, ctab, stab, q_r, k_r, v_t);

  // attention v8: KVBLK=128, 160 KB LDS, 1 block/CU, half the tile bodies
  attn_fwd<<<dim3(512), 512, 0, stream>>>(q_r, k_r, v_t, Obuf);

  gemm_bt<true><<<dim3(16, 32), 256, 0, stream>>>(Obuf, wprojb, (void*)out, BT_, C_, C_);
}